// Round 6
// baseline (29.747 us; speedup 1.0000x reference)
//
#include <hip/hip_runtime.h>
#include <math.h>

// out[b,n,e] = BOUND * tanh( slope/BOUND * w_scale * (sum_d x[d]*w[d][e]) / max(sqrt(sum_d w[d][e]^2), 1e-12) )
// B*N = 8192 pairs, D = E = 64.
// R4 inner structure (best known): lane (dq,c) = (lane>>4, lane&15), rows d = 4k+dq;
// per-k the wave's 64 float4 nt-loads form ONE contiguous 1 KB segment.
// R6 change: each wave processes NPW=4 CONSECUTIVE bn pairs (64 KB contiguous
// stream per wave, 256 KB per block); grid 2048 -> 512 blocks. Tests whether
// concurrent-stream count / stream length limits the HBM read path.

#define BOUND_F 1.8477590650225735f
#define NPW 4   // bn pairs per wave, consecutive

typedef float v4f __attribute__((ext_vector_type(4)));

__global__ __launch_bounds__(256, 4) void node_matvec_kernel(
    const float* __restrict__ x,        // [BN, 64]
    const float* __restrict__ w,        // [BN, 64, 64]  (d-major, e contiguous)
    const float* __restrict__ w_scale_p,
    const float* __restrict__ slope_p,
    float* __restrict__ out,            // [BN, 64]
    int bn_total)
{
    const int wave = threadIdx.x >> 6;
    const int lane = threadIdx.x & 63;
    const int bn0  = (blockIdx.x * 4 + wave) * NPW;   // first pair of this wave's run
    if (bn0 >= bn_total) return;

    const int c  = lane & 15;   // column group: cols 4c..4c+3
    const int dq = lane >> 4;   // row phase 0..3

    const float ws = w_scale_p[0];
    const float sl = slope_p[0];
    const float s  = sl * (1.0f / BOUND_F);

#pragma unroll 1
    for (int t = 0; t < NPW; ++t) {
        const int bn = bn0 + t;

        const float xreg = x[bn * 64 + lane];
        const v4f* __restrict__ wp = (const v4f*)(w + (size_t)bn * 4096);

        v4f dot = {0.f, 0.f, 0.f, 0.f};
        v4f sq  = {0.f, 0.f, 0.f, 0.f};

#pragma unroll
        for (int k = 0; k < 16; ++k) {
            const int d = 4 * k + dq;
            const v4f  wv = __builtin_nontemporal_load(wp + d * 16 + c);
            const float xv = __shfl(xreg, d, 64);  // broadcast x[d]
            dot.x = fmaf(xv, wv.x, dot.x);
            dot.y = fmaf(xv, wv.y, dot.y);
            dot.z = fmaf(xv, wv.z, dot.z);
            dot.w = fmaf(xv, wv.w, dot.w);
            sq.x  = fmaf(wv.x, wv.x, sq.x);
            sq.y  = fmaf(wv.y, wv.y, sq.y);
            sq.z  = fmaf(wv.z, wv.z, sq.z);
            sq.w  = fmaf(wv.w, wv.w, sq.w);
        }

        // reduce the 4 row-phase partials: lanes {c, c+16, c+32, c+48}
#pragma unroll
        for (int m = 16; m <= 32; m <<= 1) {
            dot.x += __shfl_xor(dot.x, m, 64);
            dot.y += __shfl_xor(dot.y, m, 64);
            dot.z += __shfl_xor(dot.z, m, 64);
            dot.w += __shfl_xor(dot.w, m, 64);
            sq.x  += __shfl_xor(sq.x,  m, 64);
            sq.y  += __shfl_xor(sq.y,  m, 64);
            sq.z  += __shfl_xor(sq.z,  m, 64);
            sq.w  += __shfl_xor(sq.w,  m, 64);
        }

        if (dq == 0) {
            v4f o;
            o.x = BOUND_F * tanhf(s * (ws * dot.x / fmaxf(sqrtf(sq.x), 1e-12f)));
            o.y = BOUND_F * tanhf(s * (ws * dot.y / fmaxf(sqrtf(sq.y), 1e-12f)));
            o.z = BOUND_F * tanhf(s * (ws * dot.z / fmaxf(sqrtf(sq.z), 1e-12f)));
            o.w = BOUND_F * tanhf(s * (ws * dot.w / fmaxf(sqrtf(sq.w), 1e-12f)));
            __builtin_nontemporal_store(o, (v4f*)(out + (size_t)bn * 64) + c);
        }
    }
}

extern "C" void kernel_launch(void* const* d_in, const int* in_sizes, int n_in,
                              void* d_out, int out_size, void* d_ws, size_t ws_size,
                              hipStream_t stream) {
    const float* x  = (const float*)d_in[0];
    const float* w  = (const float*)d_in[1];
    const float* ws = (const float*)d_in[2];
    const float* sl = (const float*)d_in[3];
    // d_in[4] = step_counter (unused by the reference computation)
    float* out = (float*)d_out;

    const int bn_total = in_sizes[0] / 64;              // B*N = 8192
    const int pairs_per_block = 4 * NPW;                // 4 waves x NPW pairs
    const int grid = (bn_total + pairs_per_block - 1) / pairs_per_block;  // 512

    hipLaunchKernelGGL(node_matvec_kernel, dim3(grid), dim3(256), 0, stream,
                       x, w, ws, sl, out, bn_total);
}

// Round 7
// 25.806 us; speedup vs baseline: 1.1527x; 1.1527x over previous
//
#include <hip/hip_runtime.h>
#include <math.h>

// out[b,n,e] = BOUND * tanh( slope/BOUND * w_scale * (sum_d x[d]*w[d][e]) / max(sqrt(sum_d w[d][e]^2), 1e-12) )
// B*N = 8192 pairs, D = E = 64. One wave (64 lanes) per (b,n) pair.
// PROVEN-BEST CONFIG (R4, 25.7 us = 5.39 TB/s effective):
//  - lane (dq,c) = (lane>>4, lane&15): cols 4c..4c+3, rows d = 4k+dq;
//    per-k the wave's 64 float4 loads form ONE contiguous 1 KB segment.
//  - nontemporal loads on the zero-reuse 134 MB weight stream + nt store on out.
//  - 2048 blocks x 4 waves = all 8192 pairs' waves co-resident (best HBM shape:
//    many short concurrent streams; longer-streams/fewer-waves variant was -15%).
// Probed and rejected: forced 32 waves/CU + SW pipeline (neutral), shuffle-free
// 4x256B-segment layout (-23%), sc0|nt buffer loads (-5%), 4 pairs/wave (-15%).

#define BOUND_F 1.8477590650225735f

typedef float v4f __attribute__((ext_vector_type(4)));

__global__ __launch_bounds__(256, 4) void node_matvec_kernel(
    const float* __restrict__ x,        // [BN, 64]
    const float* __restrict__ w,        // [BN, 64, 64]  (d-major, e contiguous)
    const float* __restrict__ w_scale_p,
    const float* __restrict__ slope_p,
    float* __restrict__ out,            // [BN, 64]
    int bn_total)
{
    const int wave = threadIdx.x >> 6;
    const int lane = threadIdx.x & 63;
    const int bn   = blockIdx.x * 4 + wave;   // one (b,n) per wave
    if (bn >= bn_total) return;

    const int c  = lane & 15;   // column group: cols 4c..4c+3
    const int dq = lane >> 4;   // row phase 0..3

    const float xreg = x[bn * 64 + lane];

    const v4f* __restrict__ wp = (const v4f*)(w + (size_t)bn * 4096);

    v4f dot = {0.f, 0.f, 0.f, 0.f};
    v4f sq  = {0.f, 0.f, 0.f, 0.f};

#pragma unroll
    for (int k = 0; k < 16; ++k) {
        const int d = 4 * k + dq;
        const v4f  wv = __builtin_nontemporal_load(wp + d * 16 + c);  // contiguous 1KB/wave
        const float xv = __shfl(xreg, d, 64);  // broadcast x[d]
        dot.x = fmaf(xv, wv.x, dot.x);
        dot.y = fmaf(xv, wv.y, dot.y);
        dot.z = fmaf(xv, wv.z, dot.z);
        dot.w = fmaf(xv, wv.w, dot.w);
        sq.x  = fmaf(wv.x, wv.x, sq.x);
        sq.y  = fmaf(wv.y, wv.y, sq.y);
        sq.z  = fmaf(wv.z, wv.z, sq.z);
        sq.w  = fmaf(wv.w, wv.w, sq.w);
    }

    // reduce the 4 row-phase partials: lanes {c, c+16, c+32, c+48}
#pragma unroll
    for (int m = 16; m <= 32; m <<= 1) {
        dot.x += __shfl_xor(dot.x, m, 64);
        dot.y += __shfl_xor(dot.y, m, 64);
        dot.z += __shfl_xor(dot.z, m, 64);
        dot.w += __shfl_xor(dot.w, m, 64);
        sq.x  += __shfl_xor(sq.x,  m, 64);
        sq.y  += __shfl_xor(sq.y,  m, 64);
        sq.z  += __shfl_xor(sq.z,  m, 64);
        sq.w  += __shfl_xor(sq.w,  m, 64);
    }

    if (dq == 0) {
        const float ws = w_scale_p[0];
        const float sl = slope_p[0];
        const float s  = sl * (1.0f / BOUND_F);
        v4f o;
        o.x = BOUND_F * tanhf(s * (ws * dot.x / fmaxf(sqrtf(sq.x), 1e-12f)));
        o.y = BOUND_F * tanhf(s * (ws * dot.y / fmaxf(sqrtf(sq.y), 1e-12f)));
        o.z = BOUND_F * tanhf(s * (ws * dot.z / fmaxf(sqrtf(sq.z), 1e-12f)));
        o.w = BOUND_F * tanhf(s * (ws * dot.w / fmaxf(sqrtf(sq.w), 1e-12f)));
        __builtin_nontemporal_store(o, (v4f*)(out + (size_t)bn * 64) + c);
    }
}

extern "C" void kernel_launch(void* const* d_in, const int* in_sizes, int n_in,
                              void* d_out, int out_size, void* d_ws, size_t ws_size,
                              hipStream_t stream) {
    const float* x  = (const float*)d_in[0];
    const float* w  = (const float*)d_in[1];
    const float* ws = (const float*)d_in[2];
    const float* sl = (const float*)d_in[3];
    // d_in[4] = step_counter (unused by the reference computation)
    float* out = (float*)d_out;

    const int bn_total = in_sizes[0] / 64;         // B*N = 8192
    const int grid = (bn_total + 3) / 4;           // 4 waves (pairs) per block

    hipLaunchKernelGGL(node_matvec_kernel, dim3(grid), dim3(256), 0, stream,
                       x, w, ws, sl, out, bn_total);
}